// Round 6
// baseline (152.202 us; speedup 1.0000x reference)
//
#include <hip/hip_runtime.h>

#define S_DIM 128
#define R_DIM 256
#define CM 256
#define CH 32
#define CZ 128

typedef short bf16x8 __attribute__((ext_vector_type(8)));
typedef float f32x4 __attribute__((ext_vector_type(4)));
typedef unsigned short ushort_t;

static __device__ __forceinline__ unsigned short f2bf(float f) {
  union { float f; unsigned u; } v; v.f = f;
  unsigned r = v.u + 0x7FFF + ((v.u >> 16) & 1);
  return (unsigned short)(r >> 16);
}
static __device__ __forceinline__ float bf2f(unsigned short b) {
  union { unsigned u; float f; } v; v.u = ((unsigned)b) << 16;
  return v.f;
}

// async 16B global -> LDS (linear dest = wave base + lane*16; per-lane global src)
static __device__ __forceinline__ void gload_lds16(const void* g, void* l) {
  __builtin_amdgcn_global_load_lds(
      (const __attribute__((address_space(1))) void*)g,
      (__attribute__((address_space(3))) void*)l, 16, 0, 0);
}

// ---------------- prep: pw path only (64 blocks) — must precede proj.
__global__ __launch_bounds__(256) void prep_kernel(
    const float* __restrict__ W1, const float* __restrict__ b1,
    const float* __restrict__ W2, const float* __restrict__ b2,
    const float* __restrict__ gamma, const float* __restrict__ beta,
    ushort_t* __restrict__ pwT, float* __restrict__ SGCB) {
  int c = blockIdx.x;
  int cm = threadIdx.x;
  __shared__ float red[8];
  float w = (c < 32) ? W1[cm * 32 + c] : W2[cm * 32 + (c - 32)];
  unsigned short pw = f2bf(gamma[cm] * w);
  pwT[c * 256 + cm] = pw;
  float sg = bf2f(pw), cb = beta[cm] * w;
  for (int o = 32; o > 0; o >>= 1) {
    sg += __shfl_down(sg, o);
    cb += __shfl_down(cb, o);
  }
  if ((cm & 63) == 0) { red[cm >> 6] = sg; red[4 + (cm >> 6)] = cb; }
  __syncthreads();
  if (cm == 0) {
    float s = red[0] + red[1] + red[2] + red[3];
    float q = red[4] + red[5] + red[6] + red[7];
    SGCB[c] = s;
    SGCB[64 + c] = q + ((c < 32) ? b1[c] : b2[c - 32]);
  }
}

// ---------------- proj (+wout/norm prep riding the same launch):
// blocks 0..511: MFMA LN+projection (single-bf16 input, proven R5).
// 512..543: WT transpose. 544..799: reciprocal norm table.
__global__ __launch_bounds__(256) void proj_kernel(
    const float* __restrict__ m, const float* __restrict__ mask,
    const ushort_t* __restrict__ pwT, const float* __restrict__ SGCB,
    const float* __restrict__ Wout,
    ushort_t* __restrict__ aB, ushort_t* __restrict__ bB,
    ushort_t* __restrict__ WT, float* __restrict__ normT) {
  extern __shared__ char pmem[];
  int blk = blockIdx.x;
  int t = threadIdx.x;

  if (blk >= 512) {
    if (blk < 544) {
      // --- wout: WT[z][kappa] bf16, kappa = e*32+cc (Wout row ce = cc*32+e) ---
      int e = blk - 512;
      float* wS = (float*)pmem;   // [32][129] = 16.5 KB
#pragma unroll
      for (int i = 0; i < 16; ++i) {
        int idx = i * 256 + t;
        int cc = idx >> 7, z = idx & 127;
        wS[cc * 129 + z] = Wout[(size_t)(cc * 32 + e) * CZ + z];
      }
      __syncthreads();
#pragma unroll
      for (int i = 0; i < 16; ++i) {
        int idx = i * 256 + t;
        int z = idx >> 5, cc = idx & 31;
        WT[(size_t)z * 1024 + e * 32 + cc] = f2bf(wS[cc * 129 + z]);
      }
    } else {
      // --- norm table: normT[b][d] = 1 / (sum_s mask[s,b]*mask[s,d] + 1e-3)
      int b = blk - 544;
      float ps = 0.f;
      for (int s = 0; s < S_DIM; ++s)
        ps += mask[s * R_DIM + b] * mask[s * R_DIM + t];
      normT[(size_t)b * R_DIM + t] = 1.0f / (ps + 1e-3f);
    }
    return;
  }

  ushort_t* mhS = (ushort_t*)pmem;             // [64][256] bf16 = 32 KB
  __shared__ float s1S[64], s2S[64], mkS[64];

  int r = blk >> 1, sh = blk & 1;

  {
    int s = t >> 2, q = t & 3;
    const float* src = m + ((size_t)((sh * 64 + s) * R_DIM + r)) * CM + q * 64;
    float s1 = 0.f, s2 = 0.f;
#pragma unroll
    for (int i = 0; i < 8; ++i) {
      float4 v0 = *(const float4*)(src + i * 8);
      float4 v1 = *(const float4*)(src + i * 8 + 4);
      float xs[8] = {v0.x, v0.y, v0.z, v0.w, v1.x, v1.y, v1.z, v1.w};
      union { ushort_t h[8]; float4 f; } H;
#pragma unroll
      for (int j = 0; j < 8; ++j) {
        float x = xs[j];
        s1 += x; s2 += x * x;
        H.h[j] = f2bf(x);
      }
      int ch = q * 8 + i, phys = ch ^ (s & 15);   // &15: 16-slot spread
      *(float4*)&mhS[s * 256 + phys * 8] = H.f;
    }
    s1 += __shfl_xor(s1, 1); s1 += __shfl_xor(s1, 2);
    s2 += __shfl_xor(s2, 1); s2 += __shfl_xor(s2, 2);
    if (q == 0) {
      s1S[s] = s1; s2S[s] = s2;
      mkS[s] = mask[(sh * 64 + s) * R_DIM + r];
    }
  }
  __syncthreads();

  int wave = t >> 6, lane = t & 63, l16 = lane & 15, lk = lane >> 4;
  int wm = wave >> 1, wn = wave & 1;
  f32x4 zero4 = {0.f, 0.f, 0.f, 0.f};
  f32x4 acc[2][2];
  acc[0][0] = zero4; acc[0][1] = zero4; acc[1][0] = zero4; acc[1][1] = zero4;

#pragma unroll
  for (int kstep = 0; kstep < 8; ++kstep) {
    int mm = kstep * 4 + lk;
    bf16x8 bw[2];
#pragma unroll
    for (int nf = 0; nf < 2; ++nf) {
      int cr = wn * 32 + nf * 16 + l16;
      bw[nf] = *(const bf16x8*)(pwT + cr * 256 + mm * 8);   // global, L1-hot (32 KB)
    }
#pragma unroll
    for (int mf = 0; mf < 2; ++mf) {
      int srow = wm * 32 + mf * 16 + l16;
      int phys = mm ^ (srow & 15);                           // &15 matches write
      bf16x8 ah = *(const bf16x8*)&mhS[srow * 256 + phys * 8];
#pragma unroll
      for (int nf = 0; nf < 2; ++nf)
        acc[mf][nf] = __builtin_amdgcn_mfma_f32_16x16x32_bf16(ah, bw[nf], acc[mf][nf], 0, 0, 0);
    }
  }

#pragma unroll
  for (int nf = 0; nf < 2; ++nf) {
    int c = wn * 32 + nf * 16 + l16;
    float sgv = SGCB[c], cbv = SGCB[64 + c];
#pragma unroll
    for (int mf = 0; mf < 2; ++mf) {
      union { ushort_t u[4]; uint2 v; } pk;
#pragma unroll
      for (int j = 0; j < 4; ++j) {
        int s = wm * 32 + mf * 16 + lk * 4 + j;
        float mu = s1S[s] * (1.0f / CM);
        float var = s2S[s] * (1.0f / CM) - mu * mu;
        float ri = rsqrtf(var + 1e-5f);
        float val = (ri * (acc[mf][nf][j] - mu * sgv) + cbv) * mkS[s];
        pk.u[j] = f2bf(val);
      }
      int sg0 = sh * 64 + wm * 32 + mf * 16 + lk * 4;
      if (c < 32)
        *(uint2*)&aB[((size_t)(r * 32 + c)) * S_DIM + sg0] = pk.v;
      else
        *(uint2*)&bB[((size_t)(r * 32 + (c - 32))) * S_DIM + sg0] = pk.v;
    }
  }
}

// ---------------- outer: THIS ROUND — 4x4 pair tile (was 8x8) so LDS = 64 KB
// => 2 blocks/CU (4 waves/SIMD, was 2). Same phase skeleton and swizzle
// formulas as the proven R3/R5 kernel, smaller constants; no cross-wave
// reduction (R4 lesson). Grid 4096. G2 uses 2 alternating kappa-accumulators
// per wave for MFMA ILP (summed per-lane at the end — pure arithmetic).
__global__ __launch_bounds__(512, 4) void outer_mfma_kernel(
    const ushort_t* __restrict__ aB, const ushort_t* __restrict__ bB,
    const ushort_t* __restrict__ WT, const float* __restrict__ normT,
    const float* __restrict__ bout, float* __restrict__ out) {
  extern __shared__ char smem[];           // 65536 B
  __shared__ float nrm[16];
  int t = threadIdx.x;
  int lane = t & 63, wave = t >> 6;
  int l16 = lane & 15, lk = lane >> 4;

  int bid = blockIdx.x;
  int swz = (bid & 7) * 512 + (bid >> 3);  // XCD swizzle, bijective (4096 % 8 == 0)
  int b0 = (swz >> 6) * 4, d0 = (swz & 63) * 4;

  // --- staging: A tile (4 b x 32 cc = 128 rows) -> [0,32K); B -> [32K,64K) ---
  {
    const ushort_t* srcA = aB + (size_t)b0 * 32 * S_DIM;
    const ushort_t* srcB = bB + (size_t)d0 * 32 * S_DIM;
#pragma unroll
    for (int i = 0; i < 8; ++i) {
      int cid = t + i * 512;                // 0..4095 chunks (16B each)
      int q = cid & 2047, row = q >> 4, pm = q & 15;
      int lg = pm ^ (row & 15);             // pre-swizzled source
      const ushort_t* src = (cid & 2048) ? srcB : srcA;   // uniform per wave
      gload_lds16(src + (size_t)row * S_DIM + lg * 8, smem + cid * 16);
    }
  }

  // --- nrm[p] = reciprocal norm, p = (b-sub)*4 + (d-sub), 16 entries ---
  if (t < 16) nrm[t] = normT[(size_t)(b0 + (t >> 2)) * R_DIM + d0 + (t & 3)];

  __syncthreads();   // drains vmcnt for global_load_lds

  // --- G1: wave (wm 0..1, wn 0..3) -> M rows [wm*64,+64), N cols [wn*32,+32) ---
  int wm = wave >> 2, wn = wave & 3;
  f32x4 zero4 = {0.f, 0.f, 0.f, 0.f};
  f32x4 acc[4][2];
#pragma unroll
  for (int i = 0; i < 4; ++i) {
    acc[i][0] = zero4; acc[i][1] = zero4;
  }

#pragma unroll
  for (int ks = 0; ks < 4; ++ks) {
    int mm = ks * 4 + lk;
    bf16x8 af[4], bf[2];
#pragma unroll
    for (int r = 0; r < 4; ++r) {
      int row = wm * 64 + r * 16 + l16;
      af[r] = *(const bf16x8*)(smem + row * 256 + ((mm ^ (row & 15)) << 4));
    }
#pragma unroll
    for (int c = 0; c < 2; ++c) {
      int row = wn * 32 + c * 16 + l16;
      bf[c] = *(const bf16x8*)(smem + 32768 + row * 256 + ((mm ^ (row & 15)) << 4));
    }
#pragma unroll
    for (int r = 0; r < 4; ++r)
#pragma unroll
      for (int c = 0; c < 2; ++c)
        acc[r][c] = __builtin_amdgcn_mfma_f32_16x16x32_bf16(af[r], bf[c], acc[r][c], 0, 0, 0);
  }
  __syncthreads();   // all A/B reads done before P overwrite

  // --- WT prefetch (first 4 of 8 lines): flies under the transpose phase ---
  int z = wave * 16 + l16;
  const ushort_t* wtz = WT + (size_t)z * 1024;
  bf16x8 wtb[8];
  wtb[0] = *(const bf16x8*)(wtz + lk * 8);
  wtb[1] = *(const bf16x8*)(wtz + 32 + lk * 8);
  wtb[2] = *(const bf16x8*)(wtz + 64 + lk * 8);
  wtb[3] = *(const bf16x8*)(wtz + 96 + lk * 8);

  // transpose store: P[16 p][1024 kappa] bf16 at smem[0,32K), same swizzle
#define TSTORE(rr, cc_)                                                        \
  {                                                                            \
    int Mrow = wm * 64 + (rr) * 16 + lk * 4;                                   \
    int bsub = Mrow >> 5, cc = Mrow & 31;                                      \
    int Ncol = wn * 32 + (cc_) * 16 + l16;                                     \
    int dsub = Ncol >> 5, e = Ncol & 31;                                       \
    int p = bsub * 4 + dsub;                                                   \
    int chunk = e * 4 + (cc >> 3);                                             \
    int pch = chunk ^ ((chunk >> 3) & 7) ^ (p & 15);                           \
    union { ushort_t u[4]; uint2 v; } pk;                                      \
    pk.u[0] = f2bf(acc[rr][cc_][0]);                                           \
    pk.u[1] = f2bf(acc[rr][cc_][1]);                                           \
    pk.u[2] = f2bf(acc[rr][cc_][2]);                                           \
    pk.u[3] = f2bf(acc[rr][cc_][3]);                                           \
    *(uint2*)(smem + p * 2048 + pch * 16 + (cc & 4) * 2) = pk.v;               \
  }

  // --- transpose: all 8 stores, one barrier (P = 32 KB fits at once) ---
#pragma unroll
  for (int r = 0; r < 4; ++r)
#pragma unroll
    for (int ci = 0; ci < 2; ++ci) TSTORE(r, ci);
#undef TSTORE
  __syncthreads();

  // --- G2: wave owns one 16p x 16z frag; K = 1024; 2 alternating accs ---
#define ARD(kk)                                                                \
  (*(const bf16x8*)(smem + l16 * 2048 +                                        \
                    ((((kk) * 4 + lk) ^ ((((kk) * 4 + lk) >> 3) & 7) ^         \
                      (l16 & 15))                                              \
                     << 4)))

  f32x4 oc[2];
  oc[0] = zero4; oc[1] = zero4;

  wtb[4] = *(const bf16x8*)(wtz + 128 + lk * 8);
  wtb[5] = *(const bf16x8*)(wtz + 160 + lk * 8);
  wtb[6] = *(const bf16x8*)(wtz + 192 + lk * 8);
  wtb[7] = *(const bf16x8*)(wtz + 224 + lk * 8);

  bf16x8 a_cur = ARD(0), a_nxt;
#pragma unroll
  for (int ks = 0; ks < 32; ++ks) {
    bf16x8 bfr = wtb[ks & 7];
    if (ks + 8 < 32)
      wtb[ks & 7] = *(const bf16x8*)(wtz + (ks + 8) * 32 + lk * 8);
    if (ks + 1 < 32) a_nxt = ARD(ks + 1);
    oc[ks & 1] = __builtin_amdgcn_mfma_f32_16x16x32_bf16(a_cur, bfr, oc[ks & 1], 0, 0, 0);
    a_cur = a_nxt;
  }
#undef ARD

  // --- epilogue: merge kappa-split accs, add bias, multiply reciprocal ---
  float bo = bout[z];
#pragma unroll
  for (int j = 0; j < 4; ++j) {
    int p = lk * 4 + j;
    int b = b0 + (p >> 2), d = d0 + (p & 3);
    out[((size_t)(b * R_DIM + d)) * CZ + z] = (oc[0][j] + oc[1][j] + bo) * nrm[p];
  }
}

extern "C" void kernel_launch(void* const* d_in, const int* in_sizes, int n_in,
                              void* d_out, int out_size, void* d_ws, size_t ws_size,
                              hipStream_t stream) {
  const float* m     = (const float*)d_in[0];
  const float* mask  = (const float*)d_in[1];
  const float* gamma = (const float*)d_in[2];
  const float* beta  = (const float*)d_in[3];
  const float* W1    = (const float*)d_in[4];
  const float* b1    = (const float*)d_in[5];
  const float* W2    = (const float*)d_in[6];
  const float* b2    = (const float*)d_in[7];
  const float* Wout  = (const float*)d_in[8];
  const float* bout  = (const float*)d_in[9];
  float* out = (float*)d_out;

  char* ws = (char*)d_ws;
  ushort_t* aB    = (ushort_t*)ws;                                  // 2 MB
  ushort_t* bB    = (ushort_t*)(ws + (size_t)2 * 1024 * 1024);      // 2 MB
  ushort_t* WT    = (ushort_t*)(ws + (size_t)4 * 1024 * 1024);      // 256 KB
  ushort_t* pwT   = (ushort_t*)(ws + (size_t)4352 * 1024);          // 32 KB
  float*    SGCB  = (float*)   (ws + (size_t)4416 * 1024);          // 512 B
  float*    normT = (float*)   (ws + (size_t)4480 * 1024);          // 256 KB

  hipFuncSetAttribute((const void*)outer_mfma_kernel,
                      hipFuncAttributeMaxDynamicSharedMemorySize, 65536);
  hipFuncSetAttribute((const void*)proj_kernel,
                      hipFuncAttributeMaxDynamicSharedMemorySize, 32768);

  prep_kernel<<<64, 256, 0, stream>>>(W1, b1, W2, b2, gamma, beta, pwT, SGCB);
  proj_kernel<<<800, 256, 32768, stream>>>(m, mask, pwT, SGCB, Wout,
                                           aB, bB, WT, normT);
  outer_mfma_kernel<<<4096, 512, 65536, stream>>>(aB, bB, WT, normT, bout, out);
}

// Round 7
// 101.679 us; speedup vs baseline: 1.4969x; 1.4969x over previous
//
#include <hip/hip_runtime.h>

#define S_DIM 128
#define R_DIM 256
#define CM 256
#define CH 32
#define CZ 128

typedef short bf16x8 __attribute__((ext_vector_type(8)));
typedef float f32x4 __attribute__((ext_vector_type(4)));
typedef unsigned short ushort_t;

static __device__ __forceinline__ unsigned short f2bf(float f) {
  union { float f; unsigned u; } v; v.f = f;
  unsigned r = v.u + 0x7FFF + ((v.u >> 16) & 1);
  return (unsigned short)(r >> 16);
}
static __device__ __forceinline__ float bf2f(unsigned short b) {
  union { unsigned u; float f; } v; v.u = ((unsigned)b) << 16;
  return v.f;
}

// async 16B global -> LDS (linear dest = wave base + lane*16; per-lane global src)
static __device__ __forceinline__ void gload_lds16(const void* g, void* l) {
  __builtin_amdgcn_global_load_lds(
      (const __attribute__((address_space(1))) void*)g,
      (__attribute__((address_space(3))) void*)l, 16, 0, 0);
}

// ---------------- prep: pw path only (64 blocks) — must precede proj.
__global__ __launch_bounds__(256) void prep_kernel(
    const float* __restrict__ W1, const float* __restrict__ b1,
    const float* __restrict__ W2, const float* __restrict__ b2,
    const float* __restrict__ gamma, const float* __restrict__ beta,
    ushort_t* __restrict__ pwT, float* __restrict__ SGCB) {
  int c = blockIdx.x;
  int cm = threadIdx.x;
  __shared__ float red[8];
  float w = (c < 32) ? W1[cm * 32 + c] : W2[cm * 32 + (c - 32)];
  unsigned short pw = f2bf(gamma[cm] * w);
  pwT[c * 256 + cm] = pw;
  float sg = bf2f(pw), cb = beta[cm] * w;
  for (int o = 32; o > 0; o >>= 1) {
    sg += __shfl_down(sg, o);
    cb += __shfl_down(cb, o);
  }
  if ((cm & 63) == 0) { red[cm >> 6] = sg; red[4 + (cm >> 6)] = cb; }
  __syncthreads();
  if (cm == 0) {
    float s = red[0] + red[1] + red[2] + red[3];
    float q = red[4] + red[5] + red[6] + red[7];
    SGCB[c] = s;
    SGCB[64 + c] = q + ((c < 32) ? b1[c] : b2[c - 32]);
  }
}

// ---------------- proj (+wout/norm prep riding the same launch):
// blocks 0..511: MFMA LN+projection (single-bf16 input, proven R5).
// 512..543: WT transpose. 544..799: reciprocal norm table.
__global__ __launch_bounds__(256) void proj_kernel(
    const float* __restrict__ m, const float* __restrict__ mask,
    const ushort_t* __restrict__ pwT, const float* __restrict__ SGCB,
    const float* __restrict__ Wout,
    ushort_t* __restrict__ aB, ushort_t* __restrict__ bB,
    ushort_t* __restrict__ WT, float* __restrict__ normT) {
  extern __shared__ char pmem[];
  int blk = blockIdx.x;
  int t = threadIdx.x;

  if (blk >= 512) {
    if (blk < 544) {
      // --- wout: WT[z][kappa] bf16, kappa = e*32+cc (Wout row ce = cc*32+e) ---
      int e = blk - 512;
      float* wS = (float*)pmem;   // [32][129] = 16.5 KB
#pragma unroll
      for (int i = 0; i < 16; ++i) {
        int idx = i * 256 + t;
        int cc = idx >> 7, z = idx & 127;
        wS[cc * 129 + z] = Wout[(size_t)(cc * 32 + e) * CZ + z];
      }
      __syncthreads();
#pragma unroll
      for (int i = 0; i < 16; ++i) {
        int idx = i * 256 + t;
        int z = idx >> 5, cc = idx & 31;
        WT[(size_t)z * 1024 + e * 32 + cc] = f2bf(wS[cc * 129 + z]);
      }
    } else {
      // --- norm table: normT[b][d] = 1 / (sum_s mask[s,b]*mask[s,d] + 1e-3)
      int b = blk - 544;
      float ps = 0.f;
      for (int s = 0; s < S_DIM; ++s)
        ps += mask[s * R_DIM + b] * mask[s * R_DIM + t];
      normT[(size_t)b * R_DIM + t] = 1.0f / (ps + 1e-3f);
    }
    return;
  }

  ushort_t* mhS = (ushort_t*)pmem;             // [64][256] bf16 = 32 KB
  __shared__ float s1S[64], s2S[64], mkS[64];

  int r = blk >> 1, sh = blk & 1;

  {
    int s = t >> 2, q = t & 3;
    const float* src = m + ((size_t)((sh * 64 + s) * R_DIM + r)) * CM + q * 64;
    float s1 = 0.f, s2 = 0.f;
#pragma unroll
    for (int i = 0; i < 8; ++i) {
      float4 v0 = *(const float4*)(src + i * 8);
      float4 v1 = *(const float4*)(src + i * 8 + 4);
      float xs[8] = {v0.x, v0.y, v0.z, v0.w, v1.x, v1.y, v1.z, v1.w};
      union { ushort_t h[8]; float4 f; } H;
#pragma unroll
      for (int j = 0; j < 8; ++j) {
        float x = xs[j];
        s1 += x; s2 += x * x;
        H.h[j] = f2bf(x);
      }
      int ch = q * 8 + i, phys = ch ^ (s & 15);   // &15: 16-slot spread
      *(float4*)&mhS[s * 256 + phys * 8] = H.f;
    }
    s1 += __shfl_xor(s1, 1); s1 += __shfl_xor(s1, 2);
    s2 += __shfl_xor(s2, 1); s2 += __shfl_xor(s2, 2);
    if (q == 0) {
      s1S[s] = s1; s2S[s] = s2;
      mkS[s] = mask[(sh * 64 + s) * R_DIM + r];
    }
  }
  __syncthreads();

  int wave = t >> 6, lane = t & 63, l16 = lane & 15, lk = lane >> 4;
  int wm = wave >> 1, wn = wave & 1;
  f32x4 zero4 = {0.f, 0.f, 0.f, 0.f};
  f32x4 acc[2][2];
  acc[0][0] = zero4; acc[0][1] = zero4; acc[1][0] = zero4; acc[1][1] = zero4;

#pragma unroll
  for (int kstep = 0; kstep < 8; ++kstep) {
    int mm = kstep * 4 + lk;
    bf16x8 bw[2];
#pragma unroll
    for (int nf = 0; nf < 2; ++nf) {
      int cr = wn * 32 + nf * 16 + l16;
      bw[nf] = *(const bf16x8*)(pwT + cr * 256 + mm * 8);   // global, L1-hot (32 KB)
    }
#pragma unroll
    for (int mf = 0; mf < 2; ++mf) {
      int srow = wm * 32 + mf * 16 + l16;
      int phys = mm ^ (srow & 15);                           // &15 matches write
      bf16x8 ah = *(const bf16x8*)&mhS[srow * 256 + phys * 8];
#pragma unroll
      for (int nf = 0; nf < 2; ++nf)
        acc[mf][nf] = __builtin_amdgcn_mfma_f32_16x16x32_bf16(ah, bw[nf], acc[mf][nf], 0, 0, 0);
    }
  }

#pragma unroll
  for (int nf = 0; nf < 2; ++nf) {
    int c = wn * 32 + nf * 16 + l16;
    float sgv = SGCB[c], cbv = SGCB[64 + c];
#pragma unroll
    for (int mf = 0; mf < 2; ++mf) {
      union { ushort_t u[4]; uint2 v; } pk;
#pragma unroll
      for (int j = 0; j < 4; ++j) {
        int s = wm * 32 + mf * 16 + lk * 4 + j;
        float mu = s1S[s] * (1.0f / CM);
        float var = s2S[s] * (1.0f / CM) - mu * mu;
        float ri = rsqrtf(var + 1e-5f);
        float val = (ri * (acc[mf][nf][j] - mu * sgv) + cbv) * mkS[s];
        pk.u[j] = f2bf(val);
      }
      int sg0 = sh * 64 + wm * 32 + mf * 16 + lk * 4;
      if (c < 32)
        *(uint2*)&aB[((size_t)(r * 32 + c)) * S_DIM + sg0] = pk.v;
      else
        *(uint2*)&bB[((size_t)(r * 32 + (c - 32))) * S_DIM + sg0] = pk.v;
    }
  }
}

// ---------------- outer: 8x8 pair tile (R6's 4x4 reverted — reuse > occupancy).
// THIS ROUND: R2's correctness-proven G2 remap (32p x 32z per wave -> halves
// G2 P LDS reads) combined with the two fixes its first outing lacked:
//   * depth-8 WT prefetch on BOTH z-streams (wt0[8]/wt1[8], ~620cy lead > L2 lat)
//   * &15 swizzles everywhere (R3-proven, conflicts 6.8M -> 1.0M)
__global__ __launch_bounds__(512, 2) void outer_mfma_kernel(
    const ushort_t* __restrict__ aB, const ushort_t* __restrict__ bB,
    const ushort_t* __restrict__ WT, const float* __restrict__ normT,
    const float* __restrict__ bout, float* __restrict__ out) {
  extern __shared__ char smem[];           // 131072 B
  __shared__ float nrm[64];
  int t = threadIdx.x;
  int lane = t & 63, wave = t >> 6;
  int l16 = lane & 15, lk = lane >> 4;

  int bid = blockIdx.x;
  int swz = (bid & 7) * 128 + (bid >> 3);  // XCD swizzle, bijective (1024 % 8 == 0)
  int b0 = (swz >> 5) * 8, d0 = (swz & 31) * 8;

  // --- staging: async global->LDS, 16B per lane per issue ---
  {
    const ushort_t* srcA = aB + (size_t)b0 * 32 * S_DIM;
    const ushort_t* srcB = bB + (size_t)d0 * 32 * S_DIM;
#pragma unroll
    for (int i = 0; i < 16; ++i) {
      int cid = t + i * 512;                // 0..8191 chunks (16B each)
      int q = cid & 4095, row = q >> 4, pm = q & 15;
      int lg = pm ^ (row & 15);             // pre-swizzled source
      const ushort_t* src = (cid & 4096) ? srcB : srcA;   // uniform per i
      gload_lds16(src + (size_t)row * S_DIM + lg * 8, smem + cid * 16);
    }
  }

  // --- nrm[p] = reciprocal norm from precomputed table ---
  if (t < 64) nrm[t] = normT[(size_t)(b0 + (t >> 3)) * R_DIM + d0 + (t & 7)];

  __syncthreads();   // drains vmcnt for global_load_lds

  // --- G1: wave (wm 0..3, wn 0..1) -> M rows [wm*64,+64), N cols [wn*128,+128) ---
  int wm = wave >> 1, wn = wave & 1;
  f32x4 zero4 = {0.f, 0.f, 0.f, 0.f};
  f32x4 acc[4][8];
#pragma unroll
  for (int i = 0; i < 4; ++i)
#pragma unroll
    for (int j = 0; j < 8; ++j) acc[i][j] = zero4;

#pragma unroll
  for (int ks = 0; ks < 4; ++ks) {
    int mm = ks * 4 + lk;
    bf16x8 af[4], bf[8];
#pragma unroll
    for (int r = 0; r < 4; ++r) {
      int row = wm * 64 + r * 16 + l16;
      af[r] = *(const bf16x8*)(smem + row * 256 + ((mm ^ (row & 15)) << 4));
    }
#pragma unroll
    for (int c = 0; c < 8; ++c) {
      int row = wn * 128 + c * 16 + l16;
      bf[c] = *(const bf16x8*)(smem + 65536 + row * 256 + ((mm ^ (row & 15)) << 4));
    }
#pragma unroll
    for (int r = 0; r < 4; ++r)
#pragma unroll
      for (int c = 0; c < 8; ++c)
        acc[r][c] = __builtin_amdgcn_mfma_f32_16x16x32_bf16(af[r], bf[c], acc[r][c], 0, 0, 0);
  }
  __syncthreads();   // all A/B reads done before overwrite

  // --- G2 geometry (32p x 32z per wave): wp in {0,1}, wz in {0..3} ---
  int wp = wave >> 2, wz = wave & 3;
  int z0 = wz * 32 + l16;                  // zf=0 column; zf=1 is z0+16
  const ushort_t* wtz0 = WT + (size_t)z0 * 1024;
  const ushort_t* wtz1 = wtz0 + (size_t)16 * 1024;

  // --- WT prefetch: first 4 of 8 lines per stream, under the transpose ---
  bf16x8 wt0[8], wt1[8];
#pragma unroll
  for (int i = 0; i < 4; ++i) {
    wt0[i] = *(const bf16x8*)(wtz0 + i * 32 + lk * 8);
    wt1[i] = *(const bf16x8*)(wtz1 + i * 32 + lk * 8);
  }

  // transpose store helper (&15 swizzle on p — R3-proven formula)
#define TSTORE(rr, cc_)                                                        \
  {                                                                            \
    int Mrow = wm * 64 + (rr) * 16 + lk * 4;                                   \
    int bsub = Mrow >> 5, cc = Mrow & 31;                                      \
    int Ncol = wn * 128 + (cc_) * 16 + l16;                                    \
    int dsub = Ncol >> 5, e = Ncol & 31;                                       \
    int p = bsub * 8 + dsub;                                                   \
    int chunk = e * 4 + (cc >> 3);                                             \
    int pch = chunk ^ ((chunk >> 3) & 7) ^ (p & 15);                           \
    union { ushort_t u[4]; uint2 v; } pk;                                      \
    pk.u[0] = f2bf(acc[rr][cc_][0]);                                           \
    pk.u[1] = f2bf(acc[rr][cc_][1]);                                           \
    pk.u[2] = f2bf(acc[rr][cc_][2]);                                           \
    pk.u[3] = f2bf(acc[rr][cc_][3]);                                           \
    *(uint2*)(smem + p * 2048 + pch * 16 + (cc & 4) * 2) = pk.v;               \
  }

  // --- transpose half 0: c even -> kappa < 512 ---
#pragma unroll
  for (int r = 0; r < 4; ++r)
#pragma unroll
    for (int ci = 0; ci < 4; ++ci) TSTORE(r, ci * 2);
  __syncthreads();

  // --- remaining WT prefetch (lines 4..7 per stream) + transpose half 1 ---
#pragma unroll
  for (int i = 4; i < 8; ++i) {
    wt0[i] = *(const bf16x8*)(wtz0 + i * 32 + lk * 8);
    wt1[i] = *(const bf16x8*)(wtz1 + i * 32 + lk * 8);
  }
#pragma unroll
  for (int r = 0; r < 4; ++r)
#pragma unroll
    for (int ci = 0; ci < 4; ++ci) TSTORE(r, ci * 2 + 1);
#undef TSTORE

  // --- G2: wave owns 2 p-frags x 2 z-frags; K = 1024; 8-deep dual rotation ---
#define ARD(kk, pf)                                                            \
  (*(const bf16x8*)(smem + (wp * 32 + (pf) * 16 + l16) * 2048 +                \
                    ((((kk) * 4 + lk) ^ ((((kk) * 4 + lk) >> 3) & 7) ^         \
                      ((wp * 32 + (pf) * 16 + l16) & 15))                      \
                     << 4)))

  f32x4 oc[2][2];
  oc[0][0] = zero4; oc[0][1] = zero4; oc[1][0] = zero4; oc[1][1] = zero4;

  bf16x8 a_cur[2], a_nxt[2];
#pragma unroll
  for (int pf = 0; pf < 2; ++pf) a_cur[pf] = ARD(0, pf);

#pragma unroll
  for (int ks = 0; ks < 16; ++ks) {        // reads kappa < 512 only
    bf16x8 br0 = wt0[ks & 7], br1 = wt1[ks & 7];
    if (ks + 8 < 32) {
      wt0[ks & 7] = *(const bf16x8*)(wtz0 + (ks + 8) * 32 + lk * 8);
      wt1[ks & 7] = *(const bf16x8*)(wtz1 + (ks + 8) * 32 + lk * 8);
    }
    if (ks + 1 < 16) {
#pragma unroll
      for (int pf = 0; pf < 2; ++pf) a_nxt[pf] = ARD(ks + 1, pf);
    }
#pragma unroll
    for (int pf = 0; pf < 2; ++pf) {
      oc[pf][0] = __builtin_amdgcn_mfma_f32_16x16x32_bf16(a_cur[pf], br0, oc[pf][0], 0, 0, 0);
      oc[pf][1] = __builtin_amdgcn_mfma_f32_16x16x32_bf16(a_cur[pf], br1, oc[pf][1], 0, 0, 0);
    }
    a_cur[0] = a_nxt[0]; a_cur[1] = a_nxt[1];
  }
  __syncthreads();   // transpose half-1 visible

#pragma unroll
  for (int pf = 0; pf < 2; ++pf) a_cur[pf] = ARD(16, pf);
#pragma unroll
  for (int ks = 16; ks < 32; ++ks) {
    bf16x8 br0 = wt0[ks & 7], br1 = wt1[ks & 7];
    if (ks + 8 < 32) {
      wt0[ks & 7] = *(const bf16x8*)(wtz0 + (ks + 8) * 32 + lk * 8);
      wt1[ks & 7] = *(const bf16x8*)(wtz1 + (ks + 8) * 32 + lk * 8);
    }
    if (ks + 1 < 32) {
#pragma unroll
      for (int pf = 0; pf < 2; ++pf) a_nxt[pf] = ARD(ks + 1, pf);
    }
#pragma unroll
    for (int pf = 0; pf < 2; ++pf) {
      oc[pf][0] = __builtin_amdgcn_mfma_f32_16x16x32_bf16(a_cur[pf], br0, oc[pf][0], 0, 0, 0);
      oc[pf][1] = __builtin_amdgcn_mfma_f32_16x16x32_bf16(a_cur[pf], br1, oc[pf][1], 0, 0, 0);
    }
    a_cur[0] = a_nxt[0]; a_cur[1] = a_nxt[1];
  }
#undef ARD

  // --- epilogue: nrm[] holds reciprocals -> multiply ---
  float bo0 = bout[z0], bo1 = bout[z0 + 16];
#pragma unroll
  for (int pf = 0; pf < 2; ++pf) {
#pragma unroll
    for (int j = 0; j < 4; ++j) {
      int p = wp * 32 + pf * 16 + lk * 4 + j;
      int b = b0 + (p >> 3), d = d0 + (p & 7);
      float rn = nrm[p];
      size_t base = ((size_t)(b * R_DIM + d)) * CZ;
      out[base + z0]      = (oc[pf][0][j] + bo0) * rn;
      out[base + z0 + 16] = (oc[pf][1][j] + bo1) * rn;
    }
  }
}

extern "C" void kernel_launch(void* const* d_in, const int* in_sizes, int n_in,
                              void* d_out, int out_size, void* d_ws, size_t ws_size,
                              hipStream_t stream) {
  const float* m     = (const float*)d_in[0];
  const float* mask  = (const float*)d_in[1];
  const float* gamma = (const float*)d_in[2];
  const float* beta  = (const float*)d_in[3];
  const float* W1    = (const float*)d_in[4];
  const float* b1    = (const float*)d_in[5];
  const float* W2    = (const float*)d_in[6];
  const float* b2    = (const float*)d_in[7];
  const float* Wout  = (const float*)d_in[8];
  const float* bout  = (const float*)d_in[9];
  float* out = (float*)d_out;

  char* ws = (char*)d_ws;
  ushort_t* aB    = (ushort_t*)ws;                                  // 2 MB
  ushort_t* bB    = (ushort_t*)(ws + (size_t)2 * 1024 * 1024);      // 2 MB
  ushort_t* WT    = (ushort_t*)(ws + (size_t)4 * 1024 * 1024);      // 256 KB
  ushort_t* pwT   = (ushort_t*)(ws + (size_t)4352 * 1024);          // 32 KB
  float*    SGCB  = (float*)   (ws + (size_t)4416 * 1024);          // 512 B
  float*    normT = (float*)   (ws + (size_t)4480 * 1024);          // 256 KB

  hipFuncSetAttribute((const void*)outer_mfma_kernel,
                      hipFuncAttributeMaxDynamicSharedMemorySize, 131072);
  hipFuncSetAttribute((const void*)proj_kernel,
                      hipFuncAttributeMaxDynamicSharedMemorySize, 32768);

  prep_kernel<<<64, 256, 0, stream>>>(W1, b1, W2, b2, gamma, beta, pwT, SGCB);
  proj_kernel<<<800, 256, 32768, stream>>>(m, mask, pwT, SGCB, Wout,
                                           aB, bB, WT, normT);
  outer_mfma_kernel<<<1024, 512, 131072, stream>>>(aB, bB, WT, normT, bout, out);
}

// Round 8
// 81.682 us; speedup vs baseline: 1.8633x; 1.2448x over previous
//
#include <hip/hip_runtime.h>

#define S_DIM 128
#define R_DIM 256
#define CM 256
#define CH 32
#define CZ 128

typedef short bf16x8 __attribute__((ext_vector_type(8)));
typedef float f32x4 __attribute__((ext_vector_type(4)));
typedef unsigned short ushort_t;

static __device__ __forceinline__ unsigned short f2bf(float f) {
  union { float f; unsigned u; } v; v.f = f;
  unsigned r = v.u + 0x7FFF + ((v.u >> 16) & 1);
  return (unsigned short)(r >> 16);
}
static __device__ __forceinline__ float bf2f(unsigned short b) {
  union { unsigned u; float f; } v; v.u = ((unsigned)b) << 16;
  return v.f;
}

// async 16B global -> LDS (linear dest = wave base + lane*16; per-lane global src)
static __device__ __forceinline__ void gload_lds16(const void* g, void* l) {
  __builtin_amdgcn_global_load_lds(
      (const __attribute__((address_space(1))) void*)g,
      (__attribute__((address_space(3))) void*)l, 16, 0, 0);
}

// ---------------- prep: pw path only (64 blocks) — must precede proj.
__global__ __launch_bounds__(256) void prep_kernel(
    const float* __restrict__ W1, const float* __restrict__ b1,
    const float* __restrict__ W2, const float* __restrict__ b2,
    const float* __restrict__ gamma, const float* __restrict__ beta,
    ushort_t* __restrict__ pwT, float* __restrict__ SGCB) {
  int c = blockIdx.x;
  int cm = threadIdx.x;
  __shared__ float red[8];
  float w = (c < 32) ? W1[cm * 32 + c] : W2[cm * 32 + (c - 32)];
  unsigned short pw = f2bf(gamma[cm] * w);
  pwT[c * 256 + cm] = pw;
  float sg = bf2f(pw), cb = beta[cm] * w;
  for (int o = 32; o > 0; o >>= 1) {
    sg += __shfl_down(sg, o);
    cb += __shfl_down(cb, o);
  }
  if ((cm & 63) == 0) { red[cm >> 6] = sg; red[4 + (cm >> 6)] = cb; }
  __syncthreads();
  if (cm == 0) {
    float s = red[0] + red[1] + red[2] + red[3];
    float q = red[4] + red[5] + red[6] + red[7];
    SGCB[c] = s;
    SGCB[64 + c] = q + ((c < 32) ? b1[c] : b2[c - 32]);
  }
}

// ---------------- proj (+wout/norm prep riding the same launch):
// THIS ROUND: compute split 512 -> 1024 blocks (32 s-rows each) for occupancy
// (2 -> ~6-8 blocks/CU) during the HBM-latency-exposed m gather. Same
// load/stats/MFMA/store pattern as the proven R5 proj, constants halved.
// blocks 0..1023: LN+projection. 1024..1055: WT transpose. 1056..1311: norm.
__global__ __launch_bounds__(256) void proj_kernel(
    const float* __restrict__ m, const float* __restrict__ mask,
    const ushort_t* __restrict__ pwT, const float* __restrict__ SGCB,
    const float* __restrict__ Wout,
    ushort_t* __restrict__ aB, ushort_t* __restrict__ bB,
    ushort_t* __restrict__ WT, float* __restrict__ normT) {
  extern __shared__ char pmem[];
  int blk = blockIdx.x;
  int t = threadIdx.x;

  if (blk >= 1024) {
    if (blk < 1056) {
      // --- wout: WT[z][kappa] bf16, kappa = e*32+cc (Wout row ce = cc*32+e) ---
      int e = blk - 1024;
      float* wS = (float*)pmem;   // [32][129] = 16.5 KB
#pragma unroll
      for (int i = 0; i < 16; ++i) {
        int idx = i * 256 + t;
        int cc = idx >> 7, z = idx & 127;
        wS[cc * 129 + z] = Wout[(size_t)(cc * 32 + e) * CZ + z];
      }
      __syncthreads();
#pragma unroll
      for (int i = 0; i < 16; ++i) {
        int idx = i * 256 + t;
        int z = idx >> 5, cc = idx & 31;
        WT[(size_t)z * 1024 + e * 32 + cc] = f2bf(wS[cc * 129 + z]);
      }
    } else {
      // --- norm table: normT[b][d] = 1 / (sum_s mask[s,b]*mask[s,d] + 1e-3)
      int b = blk - 1056;
      float ps = 0.f;
      for (int s = 0; s < S_DIM; ++s)
        ps += mask[s * R_DIM + b] * mask[s * R_DIM + t];
      normT[(size_t)b * R_DIM + t] = 1.0f / (ps + 1e-3f);
    }
    return;
  }

  ushort_t* mhS = (ushort_t*)pmem;             // [32][256] bf16 = 16 KB
  __shared__ float s1S[32], s2S[32], mkS[32];

  int r = blk >> 2, sq = blk & 3;              // 32 s-rows: sq*32 .. sq*32+31

  {
    int s = t >> 3, q = t & 7;                 // 8 threads/row, 32 cols each
    const float* src = m + ((size_t)((sq * 32 + s) * R_DIM + r)) * CM + q * 32;
    float s1 = 0.f, s2 = 0.f;
#pragma unroll
    for (int i = 0; i < 4; ++i) {
      float4 v0 = *(const float4*)(src + i * 8);
      float4 v1 = *(const float4*)(src + i * 8 + 4);
      float xs[8] = {v0.x, v0.y, v0.z, v0.w, v1.x, v1.y, v1.z, v1.w};
      union { ushort_t h[8]; float4 f; } H;
#pragma unroll
      for (int j = 0; j < 8; ++j) {
        float x = xs[j];
        s1 += x; s2 += x * x;
        H.h[j] = f2bf(x);
      }
      int ch = q * 4 + i, phys = ch ^ (s & 15);   // 16-slot spread (R3-proven)
      *(float4*)&mhS[s * 256 + phys * 8] = H.f;
    }
    s1 += __shfl_xor(s1, 1); s1 += __shfl_xor(s1, 2); s1 += __shfl_xor(s1, 4);
    s2 += __shfl_xor(s2, 1); s2 += __shfl_xor(s2, 2); s2 += __shfl_xor(s2, 4);
    if ((t & 7) == 0) {
      s1S[s] = s1; s2S[s] = s2;
      mkS[s] = mask[(sq * 32 + s) * R_DIM + r];
    }
  }
  __syncthreads();

  int wave = t >> 6, lane = t & 63, l16 = lane & 15, lk = lane >> 4;
  int wm = wave >> 1, wn = wave & 1;           // M rows [wm*16,+16), N cols [wn*32,+32)
  f32x4 zero4 = {0.f, 0.f, 0.f, 0.f};
  f32x4 acc[2];
  acc[0] = zero4; acc[1] = zero4;

#pragma unroll
  for (int kstep = 0; kstep < 8; ++kstep) {
    int mm = kstep * 4 + lk;
    bf16x8 bw[2];
#pragma unroll
    for (int nf = 0; nf < 2; ++nf) {
      int cr = wn * 32 + nf * 16 + l16;
      bw[nf] = *(const bf16x8*)(pwT + cr * 256 + mm * 8);   // global, L1-hot (32 KB)
    }
    int srow = wm * 16 + l16;
    int phys = mm ^ (srow & 15);                             // matches write
    bf16x8 ah = *(const bf16x8*)&mhS[srow * 256 + phys * 8];
#pragma unroll
    for (int nf = 0; nf < 2; ++nf)
      acc[nf] = __builtin_amdgcn_mfma_f32_16x16x32_bf16(ah, bw[nf], acc[nf], 0, 0, 0);
  }

#pragma unroll
  for (int nf = 0; nf < 2; ++nf) {
    int c = wn * 32 + nf * 16 + l16;
    float sgv = SGCB[c], cbv = SGCB[64 + c];
    union { ushort_t u[4]; uint2 v; } pk;
#pragma unroll
    for (int j = 0; j < 4; ++j) {
      int s = wm * 16 + lk * 4 + j;
      float mu = s1S[s] * (1.0f / CM);
      float var = s2S[s] * (1.0f / CM) - mu * mu;
      float ri = rsqrtf(var + 1e-5f);
      float val = (ri * (acc[nf][j] - mu * sgv) + cbv) * mkS[s];
      pk.u[j] = f2bf(val);
    }
    int sg0 = sq * 32 + wm * 16 + lk * 4;
    if (c < 32)
      *(uint2*)&aB[((size_t)(r * 32 + c)) * S_DIM + sg0] = pk.v;
    else
      *(uint2*)&bB[((size_t)(r * 32 + (c - 32))) * S_DIM + sg0] = pk.v;
  }
}

// ---------------- outer: 8x8 pair tile — PROVEN R5 STRUCTURE, byte-identical.
// (R7 re-proved the G2 32px32z remap regresses ~24 µs regardless of prefetch
// depth/swizzle; R6 proved 4x4 tile loses reuse; R4's 16-wave kh-split raced.
// The R0 G2 mapping + depth-8 WT rotation + &15 swizzles at 60.0 µs stands.)
__global__ __launch_bounds__(512, 2) void outer_mfma_kernel(
    const ushort_t* __restrict__ aB, const ushort_t* __restrict__ bB,
    const ushort_t* __restrict__ WT, const float* __restrict__ normT,
    const float* __restrict__ bout, float* __restrict__ out) {
  extern __shared__ char smem[];           // 131072 B
  __shared__ float nrm[64];
  int t = threadIdx.x;
  int lane = t & 63, wave = t >> 6;
  int l16 = lane & 15, lk = lane >> 4;

  int bid = blockIdx.x;
  int swz = (bid & 7) * 128 + (bid >> 3);  // XCD swizzle, bijective (1024 % 8 == 0)
  int b0 = (swz >> 5) * 8, d0 = (swz & 31) * 8;

  // --- staging: async global->LDS, 16B per lane per issue ---
  {
    const ushort_t* srcA = aB + (size_t)b0 * 32 * S_DIM;
    const ushort_t* srcB = bB + (size_t)d0 * 32 * S_DIM;
#pragma unroll
    for (int i = 0; i < 16; ++i) {
      int cid = t + i * 512;                // 0..8191 chunks (16B each)
      int q = cid & 4095, row = q >> 4, pm = q & 15;
      int lg = pm ^ (row & 15);             // pre-swizzled source
      const ushort_t* src = (cid & 4096) ? srcB : srcA;   // uniform per i
      gload_lds16(src + (size_t)row * S_DIM + lg * 8, smem + cid * 16);
    }
  }

  // --- nrm[p] = reciprocal norm from precomputed table ---
  if (t < 64) nrm[t] = normT[(size_t)(b0 + (t >> 3)) * R_DIM + d0 + (t & 7)];

  __syncthreads();   // drains vmcnt for global_load_lds

  // --- G1: wave (wm 0..3, wn 0..1) -> M rows [wm*64,+64), N cols [wn*128,+128) ---
  int wm = wave >> 1, wn = wave & 1;
  f32x4 zero4 = {0.f, 0.f, 0.f, 0.f};
  f32x4 acc[4][8];
#pragma unroll
  for (int i = 0; i < 4; ++i)
#pragma unroll
    for (int j = 0; j < 8; ++j) acc[i][j] = zero4;

#pragma unroll
  for (int ks = 0; ks < 4; ++ks) {
    int mm = ks * 4 + lk;
    bf16x8 af[4], bf[8];
#pragma unroll
    for (int r = 0; r < 4; ++r) {
      int row = wm * 64 + r * 16 + l16;
      af[r] = *(const bf16x8*)(smem + row * 256 + ((mm ^ (row & 15)) << 4));
    }
#pragma unroll
    for (int c = 0; c < 8; ++c) {
      int row = wn * 128 + c * 16 + l16;
      bf[c] = *(const bf16x8*)(smem + 65536 + row * 256 + ((mm ^ (row & 15)) << 4));
    }
#pragma unroll
    for (int r = 0; r < 4; ++r)
#pragma unroll
      for (int c = 0; c < 8; ++c)
        acc[r][c] = __builtin_amdgcn_mfma_f32_16x16x32_bf16(af[r], bf[c], acc[r][c], 0, 0, 0);
  }
  __syncthreads();   // all A/B reads done before overwrite

  // --- WT prefetch (first 4 of 8 lines): flies under the transpose phase ---
  int z = wave * 16 + l16;
  const ushort_t* wtz = WT + (size_t)z * 1024;
  bf16x8 wtb[8];
  wtb[0] = *(const bf16x8*)(wtz + lk * 8);
  wtb[1] = *(const bf16x8*)(wtz + 32 + lk * 8);
  wtb[2] = *(const bf16x8*)(wtz + 64 + lk * 8);
  wtb[3] = *(const bf16x8*)(wtz + 96 + lk * 8);

  // transpose store helper (&15 swizzle on p)
#define TSTORE(rr, cc_)                                                        \
  {                                                                            \
    int Mrow = wm * 64 + (rr) * 16 + lk * 4;                                   \
    int bsub = Mrow >> 5, cc = Mrow & 31;                                      \
    int Ncol = wn * 128 + (cc_) * 16 + l16;                                    \
    int dsub = Ncol >> 5, e = Ncol & 31;                                       \
    int p = bsub * 8 + dsub;                                                   \
    int chunk = e * 4 + (cc >> 3);                                             \
    int pch = chunk ^ ((chunk >> 3) & 7) ^ (p & 15);                           \
    union { ushort_t u[4]; uint2 v; } pk;                                      \
    pk.u[0] = f2bf(acc[rr][cc_][0]);                                           \
    pk.u[1] = f2bf(acc[rr][cc_][1]);                                           \
    pk.u[2] = f2bf(acc[rr][cc_][2]);                                           \
    pk.u[3] = f2bf(acc[rr][cc_][3]);                                           \
    *(uint2*)(smem + p * 2048 + pch * 16 + (cc & 4) * 2) = pk.v;               \
  }

  // --- transpose half 0: c even -> kappa < 512 ---
#pragma unroll
  for (int r = 0; r < 4; ++r)
#pragma unroll
    for (int ci = 0; ci < 4; ++ci) TSTORE(r, ci * 2);
  __syncthreads();

  // --- transpose half 1 (kappa >= 512) issued now; hides under G2 ks 0..15 ---
#pragma unroll
  for (int r = 0; r < 4; ++r)
#pragma unroll
    for (int ci = 0; ci < 4; ++ci) TSTORE(r, ci * 2 + 1);
#undef TSTORE

  // --- G2: wave owns z-frag; 4 p-frags; K = 1024; WT 8-deep rotation ---
#define ARD(ks, pf)                                                            \
  (*(const bf16x8*)(smem + ((pf) * 16 + l16) * 2048 +                          \
                    ((((ks) * 4 + lk) ^ ((((ks) * 4 + lk) >> 3) & 7) ^         \
                      (((pf) * 16 + l16) & 15))                                \
                     << 4)))

  f32x4 oc[4];
#pragma unroll
  for (int i = 0; i < 4; ++i) oc[i] = zero4;

  wtb[4] = *(const bf16x8*)(wtz + 128 + lk * 8);
  wtb[5] = *(const bf16x8*)(wtz + 160 + lk * 8);
  wtb[6] = *(const bf16x8*)(wtz + 192 + lk * 8);
  wtb[7] = *(const bf16x8*)(wtz + 224 + lk * 8);

  bf16x8 a_cur[4], a_nxt[4];
#pragma unroll
  for (int pf = 0; pf < 4; ++pf) a_cur[pf] = ARD(0, pf);

#pragma unroll
  for (int ks = 0; ks < 16; ++ks) {        // reads kappa < 512 only
    bf16x8 bfr = wtb[ks & 7];
    if (ks + 8 < 32)
      wtb[ks & 7] = *(const bf16x8*)(wtz + (ks + 8) * 32 + lk * 8);
    if (ks + 1 < 16) {
#pragma unroll
      for (int pf = 0; pf < 4; ++pf) a_nxt[pf] = ARD(ks + 1, pf);
    }
#pragma unroll
    for (int pf = 0; pf < 4; ++pf)
      oc[pf] = __builtin_amdgcn_mfma_f32_16x16x32_bf16(a_cur[pf], bfr, oc[pf], 0, 0, 0);
#pragma unroll
    for (int pf = 0; pf < 4; ++pf) a_cur[pf] = a_nxt[pf];
  }
  __syncthreads();   // transpose half-1 visible

#pragma unroll
  for (int pf = 0; pf < 4; ++pf) a_cur[pf] = ARD(16, pf);
#pragma unroll
  for (int ks = 16; ks < 32; ++ks) {
    bf16x8 bfr = wtb[ks & 7];
    if (ks + 8 < 32)
      wtb[ks & 7] = *(const bf16x8*)(wtz + (ks + 8) * 32 + lk * 8);
    if (ks + 1 < 32) {
#pragma unroll
      for (int pf = 0; pf < 4; ++pf) a_nxt[pf] = ARD(ks + 1, pf);
    }
#pragma unroll
    for (int pf = 0; pf < 4; ++pf)
      oc[pf] = __builtin_amdgcn_mfma_f32_16x16x32_bf16(a_cur[pf], bfr, oc[pf], 0, 0, 0);
#pragma unroll
    for (int pf = 0; pf < 4; ++pf) a_cur[pf] = a_nxt[pf];
  }
#undef ARD

  // --- epilogue: nrm[] holds reciprocals -> multiply ---
  float bo = bout[z];
#pragma unroll
  for (int pf = 0; pf < 4; ++pf) {
#pragma unroll
    for (int j = 0; j < 4; ++j) {
      int p = pf * 16 + lk * 4 + j;
      int b = b0 + (p >> 3), d = d0 + (p & 7);
      out[((size_t)(b * R_DIM + d)) * CZ + z] = (oc[pf][j] + bo) * nrm[p];
    }
  }
}

extern "C" void kernel_launch(void* const* d_in, const int* in_sizes, int n_in,
                              void* d_out, int out_size, void* d_ws, size_t ws_size,
                              hipStream_t stream) {
  const float* m     = (const float*)d_in[0];
  const float* mask  = (const float*)d_in[1];
  const float* gamma = (const float*)d_in[2];
  const float* beta  = (const float*)d_in[3];
  const float* W1    = (const float*)d_in[4];
  const float* b1    = (const float*)d_in[5];
  const float* W2    = (const float*)d_in[6];
  const float* b2    = (const float*)d_in[7];
  const float* Wout  = (const float*)d_in[8];
  const float* bout  = (const float*)d_in[9];
  float* out = (float*)d_out;

  char* ws = (char*)d_ws;
  ushort_t* aB    = (ushort_t*)ws;                                  // 2 MB
  ushort_t* bB    = (ushort_t*)(ws + (size_t)2 * 1024 * 1024);      // 2 MB
  ushort_t* WT    = (ushort_t*)(ws + (size_t)4 * 1024 * 1024);      // 256 KB
  ushort_t* pwT   = (ushort_t*)(ws + (size_t)4352 * 1024);          // 32 KB
  float*    SGCB  = (float*)   (ws + (size_t)4416 * 1024);          // 512 B
  float*    normT = (float*)   (ws + (size_t)4480 * 1024);          // 256 KB

  hipFuncSetAttribute((const void*)outer_mfma_kernel,
                      hipFuncAttributeMaxDynamicSharedMemorySize, 131072);
  hipFuncSetAttribute((const void*)proj_kernel,
                      hipFuncAttributeMaxDynamicSharedMemorySize, 24576);

  prep_kernel<<<64, 256, 0, stream>>>(W1, b1, W2, b2, gamma, beta, pwT, SGCB);
  proj_kernel<<<1312, 256, 24576, stream>>>(m, mask, pwT, SGCB, Wout,
                                            aB, bB, WT, normT);
  outer_mfma_kernel<<<1024, 512, 131072, stream>>>(aB, bB, WT, normT, bout, out);
}

// Round 9
// 77.760 us; speedup vs baseline: 1.9573x; 1.0504x over previous
//
#include <hip/hip_runtime.h>

#define S_DIM 128
#define R_DIM 256
#define CM 256
#define CH 32
#define CZ 128

typedef short bf16x8 __attribute__((ext_vector_type(8)));
typedef float f32x4 __attribute__((ext_vector_type(4)));
typedef unsigned short ushort_t;

static __device__ __forceinline__ unsigned short f2bf(float f) {
  union { float f; unsigned u; } v; v.f = f;
  unsigned r = v.u + 0x7FFF + ((v.u >> 16) & 1);
  return (unsigned short)(r >> 16);
}
static __device__ __forceinline__ float bf2f(unsigned short b) {
  union { unsigned u; float f; } v; v.u = ((unsigned)b) << 16;
  return v.f;
}

// async 16B global -> LDS (linear dest = wave base + lane*16; per-lane global src)
static __device__ __forceinline__ void gload_lds16(const void* g, void* l) {
  __builtin_amdgcn_global_load_lds(
      (const __attribute__((address_space(1))) void*)g,
      (__attribute__((address_space(3))) void*)l, 16, 0, 0);
}

// ---------------- prep: pw path only (64 blocks) — must precede proj.
__global__ __launch_bounds__(256) void prep_kernel(
    const float* __restrict__ W1, const float* __restrict__ b1,
    const float* __restrict__ W2, const float* __restrict__ b2,
    const float* __restrict__ gamma, const float* __restrict__ beta,
    ushort_t* __restrict__ pwT, float* __restrict__ SGCB) {
  int c = blockIdx.x;
  int cm = threadIdx.x;
  __shared__ float red[8];
  float w = (c < 32) ? W1[cm * 32 + c] : W2[cm * 32 + (c - 32)];
  unsigned short pw = f2bf(gamma[cm] * w);
  pwT[c * 256 + cm] = pw;
  float sg = bf2f(pw), cb = beta[cm] * w;
  for (int o = 32; o > 0; o >>= 1) {
    sg += __shfl_down(sg, o);
    cb += __shfl_down(cb, o);
  }
  if ((cm & 63) == 0) { red[cm >> 6] = sg; red[4 + (cm >> 6)] = cb; }
  __syncthreads();
  if (cm == 0) {
    float s = red[0] + red[1] + red[2] + red[3];
    float q = red[4] + red[5] + red[6] + red[7];
    SGCB[c] = s;
    SGCB[64 + c] = q + ((c < 32) ? b1[c] : b2[c - 32]);
  }
}

// ---------------- proj (+wout/norm prep riding the same launch):
// REVERTED to the proven R5 version (R8's 1024-block split regressed ~3.7 µs:
// halved MFMA amortization outweighed the occupancy gain).
// blocks 0..511: LN+projection. 512..543: WT transpose. 544..799: norm table.
__global__ __launch_bounds__(256) void proj_kernel(
    const float* __restrict__ m, const float* __restrict__ mask,
    const ushort_t* __restrict__ pwT, const float* __restrict__ SGCB,
    const float* __restrict__ Wout,
    ushort_t* __restrict__ aB, ushort_t* __restrict__ bB,
    ushort_t* __restrict__ WT, float* __restrict__ normT) {
  extern __shared__ char pmem[];
  int blk = blockIdx.x;
  int t = threadIdx.x;

  if (blk >= 512) {
    if (blk < 544) {
      // --- wout: WT[z][kappa] bf16, kappa = e*32+cc (Wout row ce = cc*32+e) ---
      int e = blk - 512;
      float* wS = (float*)pmem;   // [32][129] = 16.5 KB
#pragma unroll
      for (int i = 0; i < 16; ++i) {
        int idx = i * 256 + t;
        int cc = idx >> 7, z = idx & 127;
        wS[cc * 129 + z] = Wout[(size_t)(cc * 32 + e) * CZ + z];
      }
      __syncthreads();
#pragma unroll
      for (int i = 0; i < 16; ++i) {
        int idx = i * 256 + t;
        int z = idx >> 5, cc = idx & 31;
        WT[(size_t)z * 1024 + e * 32 + cc] = f2bf(wS[cc * 129 + z]);
      }
    } else {
      // --- norm table: normT[b][d] = 1 / (sum_s mask[s,b]*mask[s,d] + 1e-3)
      int b = blk - 544;
      float ps = 0.f;
      for (int s = 0; s < S_DIM; ++s)
        ps += mask[s * R_DIM + b] * mask[s * R_DIM + t];
      normT[(size_t)b * R_DIM + t] = 1.0f / (ps + 1e-3f);
    }
    return;
  }

  ushort_t* mhS = (ushort_t*)pmem;             // [64][256] bf16 = 32 KB
  __shared__ float s1S[64], s2S[64], mkS[64];

  int r = blk >> 1, sh = blk & 1;

  {
    int s = t >> 2, q = t & 3;
    const float* src = m + ((size_t)((sh * 64 + s) * R_DIM + r)) * CM + q * 64;
    float s1 = 0.f, s2 = 0.f;
#pragma unroll
    for (int i = 0; i < 8; ++i) {
      float4 v0 = *(const float4*)(src + i * 8);
      float4 v1 = *(const float4*)(src + i * 8 + 4);
      float xs[8] = {v0.x, v0.y, v0.z, v0.w, v1.x, v1.y, v1.z, v1.w};
      union { ushort_t h[8]; float4 f; } H;
#pragma unroll
      for (int j = 0; j < 8; ++j) {
        float x = xs[j];
        s1 += x; s2 += x * x;
        H.h[j] = f2bf(x);
      }
      int ch = q * 8 + i, phys = ch ^ (s & 15);   // &15: 16-slot spread
      *(float4*)&mhS[s * 256 + phys * 8] = H.f;
    }
    s1 += __shfl_xor(s1, 1); s1 += __shfl_xor(s1, 2);
    s2 += __shfl_xor(s2, 1); s2 += __shfl_xor(s2, 2);
    if (q == 0) {
      s1S[s] = s1; s2S[s] = s2;
      mkS[s] = mask[(sh * 64 + s) * R_DIM + r];
    }
  }
  __syncthreads();

  int wave = t >> 6, lane = t & 63, l16 = lane & 15, lk = lane >> 4;
  int wm = wave >> 1, wn = wave & 1;
  f32x4 zero4 = {0.f, 0.f, 0.f, 0.f};
  f32x4 acc[2][2];
  acc[0][0] = zero4; acc[0][1] = zero4; acc[1][0] = zero4; acc[1][1] = zero4;

#pragma unroll
  for (int kstep = 0; kstep < 8; ++kstep) {
    int mm = kstep * 4 + lk;
    bf16x8 bw[2];
#pragma unroll
    for (int nf = 0; nf < 2; ++nf) {
      int cr = wn * 32 + nf * 16 + l16;
      bw[nf] = *(const bf16x8*)(pwT + cr * 256 + mm * 8);   // global, L1-hot (32 KB)
    }
#pragma unroll
    for (int mf = 0; mf < 2; ++mf) {
      int srow = wm * 32 + mf * 16 + l16;
      int phys = mm ^ (srow & 15);                           // &15 matches write
      bf16x8 ah = *(const bf16x8*)&mhS[srow * 256 + phys * 8];
#pragma unroll
      for (int nf = 0; nf < 2; ++nf)
        acc[mf][nf] = __builtin_amdgcn_mfma_f32_16x16x32_bf16(ah, bw[nf], acc[mf][nf], 0, 0, 0);
    }
  }

#pragma unroll
  for (int nf = 0; nf < 2; ++nf) {
    int c = wn * 32 + nf * 16 + l16;
    float sgv = SGCB[c], cbv = SGCB[64 + c];
#pragma unroll
    for (int mf = 0; mf < 2; ++mf) {
      union { ushort_t u[4]; uint2 v; } pk;
#pragma unroll
      for (int j = 0; j < 4; ++j) {
        int s = wm * 32 + mf * 16 + lk * 4 + j;
        float mu = s1S[s] * (1.0f / CM);
        float var = s2S[s] * (1.0f / CM) - mu * mu;
        float ri = rsqrtf(var + 1e-5f);
        float val = (ri * (acc[mf][nf][j] - mu * sgv) + cbv) * mkS[s];
        pk.u[j] = f2bf(val);
      }
      int sg0 = sh * 64 + wm * 32 + mf * 16 + lk * 4;
      if (c < 32)
        *(uint2*)&aB[((size_t)(r * 32 + c)) * S_DIM + sg0] = pk.v;
      else
        *(uint2*)&bB[((size_t)(r * 32 + (c - 32))) * S_DIM + sg0] = pk.v;
    }
  }
}

// ---------------- outer: 8x8 pair tile, proven R3/R5 skeleton. THIS ROUND:
// G2 ARD prefetch deepened 1 -> 2 iterations (3-slot rotation, compile-time
// indices under full unroll). LDS read latency ~120cy vs ~35cy of MFMA per
// iteration meant the 1-deep chain exposed a stall each ks at 2 waves/SIMD.
// No barrier/mapping/traffic change. +16 VGPR (budget: 128 used / 256 cap).
__global__ __launch_bounds__(512, 2) void outer_mfma_kernel(
    const ushort_t* __restrict__ aB, const ushort_t* __restrict__ bB,
    const ushort_t* __restrict__ WT, const float* __restrict__ normT,
    const float* __restrict__ bout, float* __restrict__ out) {
  extern __shared__ char smem[];           // 131072 B
  __shared__ float nrm[64];
  int t = threadIdx.x;
  int lane = t & 63, wave = t >> 6;
  int l16 = lane & 15, lk = lane >> 4;

  int bid = blockIdx.x;
  int swz = (bid & 7) * 128 + (bid >> 3);  // XCD swizzle, bijective (1024 % 8 == 0)
  int b0 = (swz >> 5) * 8, d0 = (swz & 31) * 8;

  // --- staging: async global->LDS, 16B per lane per issue ---
  {
    const ushort_t* srcA = aB + (size_t)b0 * 32 * S_DIM;
    const ushort_t* srcB = bB + (size_t)d0 * 32 * S_DIM;
#pragma unroll
    for (int i = 0; i < 16; ++i) {
      int cid = t + i * 512;                // 0..8191 chunks (16B each)
      int q = cid & 4095, row = q >> 4, pm = q & 15;
      int lg = pm ^ (row & 15);             // pre-swizzled source
      const ushort_t* src = (cid & 4096) ? srcB : srcA;   // uniform per i
      gload_lds16(src + (size_t)row * S_DIM + lg * 8, smem + cid * 16);
    }
  }

  // --- nrm[p] = reciprocal norm from precomputed table ---
  if (t < 64) nrm[t] = normT[(size_t)(b0 + (t >> 3)) * R_DIM + d0 + (t & 7)];

  __syncthreads();   // drains vmcnt for global_load_lds

  // --- G1: wave (wm 0..3, wn 0..1) -> M rows [wm*64,+64), N cols [wn*128,+128) ---
  int wm = wave >> 1, wn = wave & 1;
  f32x4 zero4 = {0.f, 0.f, 0.f, 0.f};
  f32x4 acc[4][8];
#pragma unroll
  for (int i = 0; i < 4; ++i)
#pragma unroll
    for (int j = 0; j < 8; ++j) acc[i][j] = zero4;

#pragma unroll
  for (int ks = 0; ks < 4; ++ks) {
    int mm = ks * 4 + lk;
    bf16x8 af[4], bf[8];
#pragma unroll
    for (int r = 0; r < 4; ++r) {
      int row = wm * 64 + r * 16 + l16;
      af[r] = *(const bf16x8*)(smem + row * 256 + ((mm ^ (row & 15)) << 4));
    }
#pragma unroll
    for (int c = 0; c < 8; ++c) {
      int row = wn * 128 + c * 16 + l16;
      bf[c] = *(const bf16x8*)(smem + 65536 + row * 256 + ((mm ^ (row & 15)) << 4));
    }
#pragma unroll
    for (int r = 0; r < 4; ++r)
#pragma unroll
      for (int c = 0; c < 8; ++c)
        acc[r][c] = __builtin_amdgcn_mfma_f32_16x16x32_bf16(af[r], bf[c], acc[r][c], 0, 0, 0);
  }
  __syncthreads();   // all A/B reads done before overwrite

  // --- WT prefetch (first 4 of 8 lines): flies under the transpose phase ---
  int z = wave * 16 + l16;
  const ushort_t* wtz = WT + (size_t)z * 1024;
  bf16x8 wtb[8];
  wtb[0] = *(const bf16x8*)(wtz + lk * 8);
  wtb[1] = *(const bf16x8*)(wtz + 32 + lk * 8);
  wtb[2] = *(const bf16x8*)(wtz + 64 + lk * 8);
  wtb[3] = *(const bf16x8*)(wtz + 96 + lk * 8);

  // transpose store helper (&15 swizzle on p)
#define TSTORE(rr, cc_)                                                        \
  {                                                                            \
    int Mrow = wm * 64 + (rr) * 16 + lk * 4;                                   \
    int bsub = Mrow >> 5, cc = Mrow & 31;                                      \
    int Ncol = wn * 128 + (cc_) * 16 + l16;                                    \
    int dsub = Ncol >> 5, e = Ncol & 31;                                       \
    int p = bsub * 8 + dsub;                                                   \
    int chunk = e * 4 + (cc >> 3);                                             \
    int pch = chunk ^ ((chunk >> 3) & 7) ^ (p & 15);                           \
    union { ushort_t u[4]; uint2 v; } pk;                                      \
    pk.u[0] = f2bf(acc[rr][cc_][0]);                                           \
    pk.u[1] = f2bf(acc[rr][cc_][1]);                                           \
    pk.u[2] = f2bf(acc[rr][cc_][2]);                                           \
    pk.u[3] = f2bf(acc[rr][cc_][3]);                                           \
    *(uint2*)(smem + p * 2048 + pch * 16 + (cc & 4) * 2) = pk.v;               \
  }

  // --- transpose half 0: c even -> kappa < 512 ---
#pragma unroll
  for (int r = 0; r < 4; ++r)
#pragma unroll
    for (int ci = 0; ci < 4; ++ci) TSTORE(r, ci * 2);
  __syncthreads();

  // --- transpose half 1 (kappa >= 512) issued now; hides under G2 ks 0..15 ---
#pragma unroll
  for (int r = 0; r < 4; ++r)
#pragma unroll
    for (int ci = 0; ci < 4; ++ci) TSTORE(r, ci * 2 + 1);
#undef TSTORE

  // --- G2: wave owns z-frag; 4 p-frags; K = 1024; WT 8-deep rotation;
  //     ARD pipeline 2-deep (3-slot rotation, static indices under unroll) ---
#define ARD(ks, pf)                                                            \
  (*(const bf16x8*)(smem + ((pf) * 16 + l16) * 2048 +                          \
                    ((((ks) * 4 + lk) ^ ((((ks) * 4 + lk) >> 3) & 7) ^         \
                      (((pf) * 16 + l16) & 15))                                \
                     << 4)))

  f32x4 oc[4];
#pragma unroll
  for (int i = 0; i < 4; ++i) oc[i] = zero4;

  wtb[4] = *(const bf16x8*)(wtz + 128 + lk * 8);
  wtb[5] = *(const bf16x8*)(wtz + 160 + lk * 8);
  wtb[6] = *(const bf16x8*)(wtz + 192 + lk * 8);
  wtb[7] = *(const bf16x8*)(wtz + 224 + lk * 8);

  bf16x8 abuf[3][4];
#pragma unroll
  for (int pf = 0; pf < 4; ++pf) abuf[0][pf] = ARD(0, pf);
#pragma unroll
  for (int pf = 0; pf < 4; ++pf) abuf[1][pf] = ARD(1, pf);

#pragma unroll
  for (int ks = 0; ks < 16; ++ks) {        // reads kappa < 512 only
    bf16x8 bfr = wtb[ks & 7];
    if (ks + 8 < 32)
      wtb[ks & 7] = *(const bf16x8*)(wtz + (ks + 8) * 32 + lk * 8);
    if (ks + 2 < 16) {
#pragma unroll
      for (int pf = 0; pf < 4; ++pf) abuf[(ks + 2) % 3][pf] = ARD(ks + 2, pf);
    }
#pragma unroll
    for (int pf = 0; pf < 4; ++pf)
      oc[pf] = __builtin_amdgcn_mfma_f32_16x16x32_bf16(abuf[ks % 3][pf], bfr, oc[pf], 0, 0, 0);
  }
  __syncthreads();   // transpose half-1 visible

#pragma unroll
  for (int pf = 0; pf < 4; ++pf) abuf[0][pf] = ARD(16, pf);
#pragma unroll
  for (int pf = 0; pf < 4; ++pf) abuf[1][pf] = ARD(17, pf);

#pragma unroll
  for (int kk = 0; kk < 16; ++kk) {
    int ks = kk + 16;
    bf16x8 bfr = wtb[ks & 7];
    if (ks + 8 < 32)
      wtb[ks & 7] = *(const bf16x8*)(wtz + (ks + 8) * 32 + lk * 8);
    if (kk + 2 < 16) {
#pragma unroll
      for (int pf = 0; pf < 4; ++pf) abuf[(kk + 2) % 3][pf] = ARD(ks + 2, pf);
    }
#pragma unroll
    for (int pf = 0; pf < 4; ++pf)
      oc[pf] = __builtin_amdgcn_mfma_f32_16x16x32_bf16(abuf[kk % 3][pf], bfr, oc[pf], 0, 0, 0);
  }
#undef ARD

  // --- epilogue: nrm[] holds reciprocals -> multiply ---
  float bo = bout[z];
#pragma unroll
  for (int pf = 0; pf < 4; ++pf) {
#pragma unroll
    for (int j = 0; j < 4; ++j) {
      int p = pf * 16 + lk * 4 + j;
      int b = b0 + (p >> 3), d = d0 + (p & 7);
      out[((size_t)(b * R_DIM + d)) * CZ + z] = (oc[pf][j] + bo) * nrm[p];
    }
  }
}

extern "C" void kernel_launch(void* const* d_in, const int* in_sizes, int n_in,
                              void* d_out, int out_size, void* d_ws, size_t ws_size,
                              hipStream_t stream) {
  const float* m     = (const float*)d_in[0];
  const float* mask  = (const float*)d_in[1];
  const float* gamma = (const float*)d_in[2];
  const float* beta  = (const float*)d_in[3];
  const float* W1    = (const float*)d_in[4];
  const float* b1    = (const float*)d_in[5];
  const float* W2    = (const float*)d_in[6];
  const float* b2    = (const float*)d_in[7];
  const float* Wout  = (const float*)d_in[8];
  const float* bout  = (const float*)d_in[9];
  float* out = (float*)d_out;

  char* ws = (char*)d_ws;
  ushort_t* aB    = (ushort_t*)ws;                                  // 2 MB
  ushort_t* bB    = (ushort_t*)(ws + (size_t)2 * 1024 * 1024);      // 2 MB
  ushort_t* WT    = (ushort_t*)(ws + (size_t)4 * 1024 * 1024);      // 256 KB
  ushort_t* pwT   = (ushort_t*)(ws + (size_t)4352 * 1024);          // 32 KB
  float*    SGCB  = (float*)   (ws + (size_t)4416 * 1024);          // 512 B
  float*    normT = (float*)   (ws + (size_t)4480 * 1024);          // 256 KB

  hipFuncSetAttribute((const void*)outer_mfma_kernel,
                      hipFuncAttributeMaxDynamicSharedMemorySize, 131072);
  hipFuncSetAttribute((const void*)proj_kernel,
                      hipFuncAttributeMaxDynamicSharedMemorySize, 32768);

  prep_kernel<<<64, 256, 0, stream>>>(W1, b1, W2, b2, gamma, beta, pwT, SGCB);
  proj_kernel<<<800, 256, 32768, stream>>>(m, mask, pwT, SGCB, Wout,
                                           aB, bB, WT, normT);
  outer_mfma_kernel<<<1024, 512, 131072, stream>>>(aB, bB, WT, normT, bout, out);
}

// Round 10
// 77.707 us; speedup vs baseline: 1.9587x; 1.0007x over previous
//
#include <hip/hip_runtime.h>

#define S_DIM 128
#define R_DIM 256
#define CM 256
#define CH 32
#define CZ 128

typedef short bf16x8 __attribute__((ext_vector_type(8)));
typedef float f32x4 __attribute__((ext_vector_type(4)));
typedef unsigned short ushort_t;

static __device__ __forceinline__ unsigned short f2bf(float f) {
  union { float f; unsigned u; } v; v.f = f;
  unsigned r = v.u + 0x7FFF + ((v.u >> 16) & 1);
  return (unsigned short)(r >> 16);
}
static __device__ __forceinline__ float bf2f(unsigned short b) {
  union { unsigned u; float f; } v; v.u = ((unsigned)b) << 16;
  return v.f;
}

// async 16B global -> LDS (linear dest = wave base + lane*16; per-lane global src)
static __device__ __forceinline__ void gload_lds16(const void* g, void* l) {
  __builtin_amdgcn_global_load_lds(
      (const __attribute__((address_space(1))) void*)g,
      (__attribute__((address_space(3))) void*)l, 16, 0, 0);
}

// ---------------- prep: THIS ROUND — coalesced rewrite. Old version: 64 blocks,
// each thread gathered a W column with stride-128B scalar loads (uncoalesced,
// latency-bound). New: 8 blocks; stage W1+W2 into LDS via coalesced float4
// (pad stride 65 floats -> conflict-free cm-major reads with cm = k*32+t5);
// each block computes 8 c-columns. Semantics identical: pwT = f2bf(gamma*W),
// SGCB[c] = sum(bf2f(pw)), SGCB[64+c] = sum(beta*W) + bias.
__global__ __launch_bounds__(256) void prep_kernel(
    const float* __restrict__ W1, const float* __restrict__ b1,
    const float* __restrict__ W2, const float* __restrict__ b2,
    const float* __restrict__ gamma, const float* __restrict__ beta,
    ushort_t* __restrict__ pwT, float* __restrict__ SGCB) {
  extern __shared__ float wS[];            // [256][65] floats = 66560 B
  int blk = blockIdx.x;                    // 8 blocks x 8 c-columns
  int t = threadIdx.x;

  // --- stage W1 (cols 0..31) and W2 (cols 32..63), coalesced float4 ---
#pragma unroll
  for (int i = 0; i < 8; ++i) {
    int fid = i * 256 + t;                 // 0..2047 float4s
    int cm = fid >> 3, c4 = fid & 7;
    float4 v1 = *(const float4*)(W1 + (size_t)fid * 4);
    float4 v2 = *(const float4*)(W2 + (size_t)fid * 4);
    float* d1 = &wS[cm * 65 + c4 * 4];
    d1[0] = v1.x; d1[1] = v1.y; d1[2] = v1.z; d1[3] = v1.w;
    float* d2 = &wS[cm * 65 + 32 + c4 * 4];
    d2[0] = v2.x; d2[1] = v2.y; d2[2] = v2.z; d2[3] = v2.w;
  }
  __syncthreads();

  int c_local = t >> 5, t5 = t & 31;       // 32 threads per c-column
  int c = blk * 8 + c_local;
  float sg = 0.f, cb = 0.f;
#pragma unroll
  for (int k = 0; k < 8; ++k) {
    int cm = k * 32 + t5;                  // stride-32 cm: conflict-free reads
    float w = wS[cm * 65 + c];
    float g = gamma[cm];
    unsigned short pw = f2bf(g * w);
    pwT[c * 256 + cm] = pw;                // 2B stores, contiguous across t5
    sg += bf2f(pw);
    cb += beta[cm] * w;
  }
  // reduce over the 32-thread group (offsets <=16 stay within the half-wave)
#pragma unroll
  for (int o = 16; o > 0; o >>= 1) {
    sg += __shfl_xor(sg, o);
    cb += __shfl_xor(cb, o);
  }
  if (t5 == 0) {
    SGCB[c] = sg;
    SGCB[64 + c] = cb + ((c < 32) ? b1[c] : b2[c - 32]);
  }
}

// ---------------- proj (+wout/norm prep riding the same launch):
// proven R5 version. blocks 0..511: LN+projection. 512..543: WT transpose.
// 544..799: reciprocal norm table.
__global__ __launch_bounds__(256) void proj_kernel(
    const float* __restrict__ m, const float* __restrict__ mask,
    const ushort_t* __restrict__ pwT, const float* __restrict__ SGCB,
    const float* __restrict__ Wout,
    ushort_t* __restrict__ aB, ushort_t* __restrict__ bB,
    ushort_t* __restrict__ WT, float* __restrict__ normT) {
  extern __shared__ char pmem[];
  int blk = blockIdx.x;
  int t = threadIdx.x;

  if (blk >= 512) {
    if (blk < 544) {
      // --- wout: WT[z][kappa] bf16, kappa = e*32+cc (Wout row ce = cc*32+e) ---
      int e = blk - 512;
      float* wS = (float*)pmem;   // [32][129] = 16.5 KB
#pragma unroll
      for (int i = 0; i < 16; ++i) {
        int idx = i * 256 + t;
        int cc = idx >> 7, z = idx & 127;
        wS[cc * 129 + z] = Wout[(size_t)(cc * 32 + e) * CZ + z];
      }
      __syncthreads();
#pragma unroll
      for (int i = 0; i < 16; ++i) {
        int idx = i * 256 + t;
        int z = idx >> 5, cc = idx & 31;
        WT[(size_t)z * 1024 + e * 32 + cc] = f2bf(wS[cc * 129 + z]);
      }
    } else {
      // --- norm table: normT[b][d] = 1 / (sum_s mask[s,b]*mask[s,d] + 1e-3)
      int b = blk - 544;
      float ps = 0.f;
      for (int s = 0; s < S_DIM; ++s)
        ps += mask[s * R_DIM + b] * mask[s * R_DIM + t];
      normT[(size_t)b * R_DIM + t] = 1.0f / (ps + 1e-3f);
    }
    return;
  }

  ushort_t* mhS = (ushort_t*)pmem;             // [64][256] bf16 = 32 KB
  __shared__ float s1S[64], s2S[64], mkS[64];

  int r = blk >> 1, sh = blk & 1;

  {
    int s = t >> 2, q = t & 3;
    const float* src = m + ((size_t)((sh * 64 + s) * R_DIM + r)) * CM + q * 64;
    float s1 = 0.f, s2 = 0.f;
#pragma unroll
    for (int i = 0; i < 8; ++i) {
      float4 v0 = *(const float4*)(src + i * 8);
      float4 v1 = *(const float4*)(src + i * 8 + 4);
      float xs[8] = {v0.x, v0.y, v0.z, v0.w, v1.x, v1.y, v1.z, v1.w};
      union { ushort_t h[8]; float4 f; } H;
#pragma unroll
      for (int j = 0; j < 8; ++j) {
        float x = xs[j];
        s1 += x; s2 += x * x;
        H.h[j] = f2bf(x);
      }
      int ch = q * 8 + i, phys = ch ^ (s & 15);   // &15: 16-slot spread
      *(float4*)&mhS[s * 256 + phys * 8] = H.f;
    }
    s1 += __shfl_xor(s1, 1); s1 += __shfl_xor(s1, 2);
    s2 += __shfl_xor(s2, 1); s2 += __shfl_xor(s2, 2);
    if (q == 0) {
      s1S[s] = s1; s2S[s] = s2;
      mkS[s] = mask[(sh * 64 + s) * R_DIM + r];
    }
  }
  __syncthreads();

  int wave = t >> 6, lane = t & 63, l16 = lane & 15, lk = lane >> 4;
  int wm = wave >> 1, wn = wave & 1;
  f32x4 zero4 = {0.f, 0.f, 0.f, 0.f};
  f32x4 acc[2][2];
  acc[0][0] = zero4; acc[0][1] = zero4; acc[1][0] = zero4; acc[1][1] = zero4;

#pragma unroll
  for (int kstep = 0; kstep < 8; ++kstep) {
    int mm = kstep * 4 + lk;
    bf16x8 bw[2];
#pragma unroll
    for (int nf = 0; nf < 2; ++nf) {
      int cr = wn * 32 + nf * 16 + l16;
      bw[nf] = *(const bf16x8*)(pwT + cr * 256 + mm * 8);   // global, L1-hot (32 KB)
    }
#pragma unroll
    for (int mf = 0; mf < 2; ++mf) {
      int srow = wm * 32 + mf * 16 + l16;
      int phys = mm ^ (srow & 15);                           // &15 matches write
      bf16x8 ah = *(const bf16x8*)&mhS[srow * 256 + phys * 8];
#pragma unroll
      for (int nf = 0; nf < 2; ++nf)
        acc[mf][nf] = __builtin_amdgcn_mfma_f32_16x16x32_bf16(ah, bw[nf], acc[mf][nf], 0, 0, 0);
    }
  }

#pragma unroll
  for (int nf = 0; nf < 2; ++nf) {
    int c = wn * 32 + nf * 16 + l16;
    float sgv = SGCB[c], cbv = SGCB[64 + c];
#pragma unroll
    for (int mf = 0; mf < 2; ++mf) {
      union { ushort_t u[4]; uint2 v; } pk;
#pragma unroll
      for (int j = 0; j < 4; ++j) {
        int s = wm * 32 + mf * 16 + lk * 4 + j;
        float mu = s1S[s] * (1.0f / CM);
        float var = s2S[s] * (1.0f / CM) - mu * mu;
        float ri = rsqrtf(var + 1e-5f);
        float val = (ri * (acc[mf][nf][j] - mu * sgv) + cbv) * mkS[s];
        pk.u[j] = f2bf(val);
      }
      int sg0 = sh * 64 + wm * 32 + mf * 16 + lk * 4;
      if (c < 32)
        *(uint2*)&aB[((size_t)(r * 32 + c)) * S_DIM + sg0] = pk.v;
      else
        *(uint2*)&bB[((size_t)(r * 32 + (c - 32))) * S_DIM + sg0] = pk.v;
    }
  }
}

// ---------------- outer: 8x8 pair tile — R9 structure, byte-identical (current
// best: ~59.5 µs). Decomposition is traffic-optimal (any (p,z) rebalance raises
// WT streams = proven ~24 µs poison); occupancy pinned by P-LDS 128 KB AND
// acc[4][8] = 128 VGPR simultaneously. Depth-8 WT rotation + 2-deep ARD.
__global__ __launch_bounds__(512, 2) void outer_mfma_kernel(
    const ushort_t* __restrict__ aB, const ushort_t* __restrict__ bB,
    const ushort_t* __restrict__ WT, const float* __restrict__ normT,
    const float* __restrict__ bout, float* __restrict__ out) {
  extern __shared__ char smem[];           // 131072 B
  __shared__ float nrm[64];
  int t = threadIdx.x;
  int lane = t & 63, wave = t >> 6;
  int l16 = lane & 15, lk = lane >> 4;

  int bid = blockIdx.x;
  int swz = (bid & 7) * 128 + (bid >> 3);  // XCD swizzle, bijective (1024 % 8 == 0)
  int b0 = (swz >> 5) * 8, d0 = (swz & 31) * 8;

  // --- staging: async global->LDS, 16B per lane per issue ---
  {
    const ushort_t* srcA = aB + (size_t)b0 * 32 * S_DIM;
    const ushort_t* srcB = bB + (size_t)d0 * 32 * S_DIM;
#pragma unroll
    for (int i = 0; i < 16; ++i) {
      int cid = t + i * 512;                // 0..8191 chunks (16B each)
      int q = cid & 4095, row = q >> 4, pm = q & 15;
      int lg = pm ^ (row & 15);             // pre-swizzled source
      const ushort_t* src = (cid & 4096) ? srcB : srcA;   // uniform per i
      gload_lds16(src + (size_t)row * S_DIM + lg * 8, smem + cid * 16);
    }
  }

  // --- nrm[p] = reciprocal norm from precomputed table ---
  if (t < 64) nrm[t] = normT[(size_t)(b0 + (t >> 3)) * R_DIM + d0 + (t & 7)];

  __syncthreads();   // drains vmcnt for global_load_lds

  // --- G1: wave (wm 0..3, wn 0..1) -> M rows [wm*64,+64), N cols [wn*128,+128) ---
  int wm = wave >> 1, wn = wave & 1;
  f32x4 zero4 = {0.f, 0.f, 0.f, 0.f};
  f32x4 acc[4][8];
#pragma unroll
  for (int i = 0; i < 4; ++i)
#pragma unroll
    for (int j = 0; j < 8; ++j) acc[i][j] = zero4;

#pragma unroll
  for (int ks = 0; ks < 4; ++ks) {
    int mm = ks * 4 + lk;
    bf16x8 af[4], bf[8];
#pragma unroll
    for (int r = 0; r < 4; ++r) {
      int row = wm * 64 + r * 16 + l16;
      af[r] = *(const bf16x8*)(smem + row * 256 + ((mm ^ (row & 15)) << 4));
    }
#pragma unroll
    for (int c = 0; c < 8; ++c) {
      int row = wn * 128 + c * 16 + l16;
      bf[c] = *(const bf16x8*)(smem + 65536 + row * 256 + ((mm ^ (row & 15)) << 4));
    }
#pragma unroll
    for (int r = 0; r < 4; ++r)
#pragma unroll
      for (int c = 0; c < 8; ++c)
        acc[r][c] = __builtin_amdgcn_mfma_f32_16x16x32_bf16(af[r], bf[c], acc[r][c], 0, 0, 0);
  }
  __syncthreads();   // all A/B reads done before overwrite

  // --- WT prefetch (first 4 of 8 lines): flies under the transpose phase ---
  int z = wave * 16 + l16;
  const ushort_t* wtz = WT + (size_t)z * 1024;
  bf16x8 wtb[8];
  wtb[0] = *(const bf16x8*)(wtz + lk * 8);
  wtb[1] = *(const bf16x8*)(wtz + 32 + lk * 8);
  wtb[2] = *(const bf16x8*)(wtz + 64 + lk * 8);
  wtb[3] = *(const bf16x8*)(wtz + 96 + lk * 8);

  // transpose store helper (&15 swizzle on p)
#define TSTORE(rr, cc_)                                                        \
  {                                                                            \
    int Mrow = wm * 64 + (rr) * 16 + lk * 4;                                   \
    int bsub = Mrow >> 5, cc = Mrow & 31;                                      \
    int Ncol = wn * 128 + (cc_) * 16 + l16;                                    \
    int dsub = Ncol >> 5, e = Ncol & 31;                                       \
    int p = bsub * 8 + dsub;                                                   \
    int chunk = e * 4 + (cc >> 3);                                             \
    int pch = chunk ^ ((chunk >> 3) & 7) ^ (p & 15);                           \
    union { ushort_t u[4]; uint2 v; } pk;                                      \
    pk.u[0] = f2bf(acc[rr][cc_][0]);                                           \
    pk.u[1] = f2bf(acc[rr][cc_][1]);                                           \
    pk.u[2] = f2bf(acc[rr][cc_][2]);                                           \
    pk.u[3] = f2bf(acc[rr][cc_][3]);                                           \
    *(uint2*)(smem + p * 2048 + pch * 16 + (cc & 4) * 2) = pk.v;               \
  }

  // --- transpose half 0: c even -> kappa < 512 ---
#pragma unroll
  for (int r = 0; r < 4; ++r)
#pragma unroll
    for (int ci = 0; ci < 4; ++ci) TSTORE(r, ci * 2);
  __syncthreads();

  // --- transpose half 1 (kappa >= 512) issued now; hides under G2 ks 0..15 ---
#pragma unroll
  for (int r = 0; r < 4; ++r)
#pragma unroll
    for (int ci = 0; ci < 4; ++ci) TSTORE(r, ci * 2 + 1);
#undef TSTORE

  // --- G2: wave owns z-frag; 4 p-frags; K = 1024; WT 8-deep rotation;
  //     ARD pipeline 2-deep (3-slot rotation, static indices under unroll) ---
#define ARD(ks, pf)                                                            \
  (*(const bf16x8*)(smem + ((pf) * 16 + l16) * 2048 +                          \
                    ((((ks) * 4 + lk) ^ ((((ks) * 4 + lk) >> 3) & 7) ^         \
                      (((pf) * 16 + l16) & 15))                                \
                     << 4)))

  f32x4 oc[4];
#pragma unroll
  for (int i = 0; i < 4; ++i) oc[i] = zero4;

  wtb[4] = *(const bf16x8*)(wtz + 128 + lk * 8);
  wtb[5] = *(const bf16x8*)(wtz + 160 + lk * 8);
  wtb[6] = *(const bf16x8*)(wtz + 192 + lk * 8);
  wtb[7] = *(const bf16x8*)(wtz + 224 + lk * 8);

  bf16x8 abuf[3][4];
#pragma unroll
  for (int pf = 0; pf < 4; ++pf) abuf[0][pf] = ARD(0, pf);
#pragma unroll
  for (int pf = 0; pf < 4; ++pf) abuf[1][pf] = ARD(1, pf);

#pragma unroll
  for (int ks = 0; ks < 16; ++ks) {        // reads kappa < 512 only
    bf16x8 bfr = wtb[ks & 7];
    if (ks + 8 < 32)
      wtb[ks & 7] = *(const bf16x8*)(wtz + (ks + 8) * 32 + lk * 8);
    if (ks + 2 < 16) {
#pragma unroll
      for (int pf = 0; pf < 4; ++pf) abuf[(ks + 2) % 3][pf] = ARD(ks + 2, pf);
    }
#pragma unroll
    for (int pf = 0; pf < 4; ++pf)
      oc[pf] = __builtin_amdgcn_mfma_f32_16x16x32_bf16(abuf[ks % 3][pf], bfr, oc[pf], 0, 0, 0);
  }
  __syncthreads();   // transpose half-1 visible

#pragma unroll
  for (int pf = 0; pf < 4; ++pf) abuf[0][pf] = ARD(16, pf);
#pragma unroll
  for (int pf = 0; pf < 4; ++pf) abuf[1][pf] = ARD(17, pf);

#pragma unroll
  for (int kk = 0; kk < 16; ++kk) {
    int ks = kk + 16;
    bf16x8 bfr = wtb[ks & 7];
    if (ks + 8 < 32)
      wtb[ks & 7] = *(const bf16x8*)(wtz + (ks + 8) * 32 + lk * 8);
    if (kk + 2 < 16) {
#pragma unroll
      for (int pf = 0; pf < 4; ++pf) abuf[(kk + 2) % 3][pf] = ARD(ks + 2, pf);
    }
#pragma unroll
    for (int pf = 0; pf < 4; ++pf)
      oc[pf] = __builtin_amdgcn_mfma_f32_16x16x32_bf16(abuf[kk % 3][pf], bfr, oc[pf], 0, 0, 0);
  }
#undef ARD

  // --- epilogue: nrm[] holds reciprocals -> multiply ---
  float bo = bout[z];
#pragma unroll
  for (int pf = 0; pf < 4; ++pf) {
#pragma unroll
    for (int j = 0; j < 4; ++j) {
      int p = pf * 16 + lk * 4 + j;
      int b = b0 + (p >> 3), d = d0 + (p & 7);
      out[((size_t)(b * R_DIM + d)) * CZ + z] = (oc[pf][j] + bo) * nrm[p];
    }
  }
}

extern "C" void kernel_launch(void* const* d_in, const int* in_sizes, int n_in,
                              void* d_out, int out_size, void* d_ws, size_t ws_size,
                              hipStream_t stream) {
  const float* m     = (const float*)d_in[0];
  const float* mask  = (const float*)d_in[1];
  const float* gamma = (const float*)d_in[2];
  const float* beta  = (const float*)d_in[3];
  const float* W1    = (const float*)d_in[4];
  const float* b1    = (const float*)d_in[5];
  const float* W2    = (const float*)d_in[6];
  const float* b2    = (const float*)d_in[7];
  const float* Wout  = (const float*)d_in[8];
  const float* bout  = (const float*)d_in[9];
  float* out = (float*)d_out;

  char* ws = (char*)d_ws;
  ushort_t* aB    = (ushort_t*)ws;                                  // 2 MB
  ushort_t* bB    = (ushort_t*)(ws + (size_t)2 * 1024 * 1024);      // 2 MB
  ushort_t* WT    = (ushort_t*)(ws + (size_t)4 * 1024 * 1024);      // 256 KB
  ushort_t* pwT   = (ushort_t*)(ws + (size_t)4352 * 1024);          // 32 KB
  float*    SGCB  = (float*)   (ws + (size_t)4416 * 1024);          // 512 B
  float*    normT = (float*)   (ws + (size_t)4480 * 1024);          // 256 KB

  hipFuncSetAttribute((const void*)outer_mfma_kernel,
                      hipFuncAttributeMaxDynamicSharedMemorySize, 131072);
  hipFuncSetAttribute((const void*)proj_kernel,
                      hipFuncAttributeMaxDynamicSharedMemorySize, 32768);
  hipFuncSetAttribute((const void*)prep_kernel,
                      hipFuncAttributeMaxDynamicSharedMemorySize, 66560);

  prep_kernel<<<8, 256, 66560, stream>>>(W1, b1, W2, b2, gamma, beta, pwT, SGCB);
  proj_kernel<<<800, 256, 32768, stream>>>(m, mask, pwT, SGCB, Wout,
                                           aB, bB, WT, normT);
  outer_mfma_kernel<<<1024, 512, 131072, stream>>>(aB, bB, WT, normT, bout, out);
}